// Round 1
// 404.425 us; speedup vs baseline: 1.0214x; 1.0214x over previous
//
#include <hip/hip_runtime.h>
#include <cstdint>

#define ED 256
#define D1 128
#define D2 64
#define NC 50
#define NB 4
#define NN 4096
#define R1 16      // rows per block, mlp kernel
#define TIB 8      // i-rows per block, pair kernel
#define JT 8       // j per thread, pair kernel
#define PTH 512    // threads, pair kernel

// ---------------- Kernel 1: MLP 256 -> 128 -> 64 -> 50, writes zT[b][k][n] + |z|^2 ----------------
__global__ __launch_bounds__(256) void mlp_kernel(
    const float* __restrict__ emb,
    const float* __restrict__ W1, const float* __restrict__ b1,
    const float* __restrict__ W2, const float* __restrict__ b2,
    const float* __restrict__ W3, const float* __restrict__ b3,
    float* __restrict__ zT, float* __restrict__ sq)
{
    __shared__ __align__(16) float se[R1*ED];
    __shared__ __align__(16) float sh1[R1*D1];
    __shared__ __align__(16) float sh2[R1*D2];
    __shared__ __align__(16) float sz[R1*NC];
    const int t = threadIdx.x;
    const long row0 = (long)blockIdx.x * R1;

    // stage 16 embedding rows (contiguous) into LDS, float4
    {
        const float4* g4 = (const float4*)(emb + row0*ED);
        float4* s4 = (float4*)se;
        #pragma unroll
        for (int k = 0; k < (R1*ED/4)/256; k++)
            s4[t + k*256] = g4[t + k*256];
    }
    __syncthreads();

    // layer 1: each thread = one f column, 8 rows
    {
        const int f = t & (D1-1);
        const int half = t >> 7;
        float acc[8];
        const float bias = b1[f];
        #pragma unroll
        for (int rr = 0; rr < 8; rr++) acc[rr] = bias;
        for (int d = 0; d < ED; d += 4) {
            const float w0 = W1[(d+0)*D1 + f];
            const float w1 = W1[(d+1)*D1 + f];
            const float w2 = W1[(d+2)*D1 + f];
            const float w3 = W1[(d+3)*D1 + f];
            #pragma unroll
            for (int rr = 0; rr < 8; rr++) {
                const float4 e = *(const float4*)&se[(half*8+rr)*ED + d];
                acc[rr] = fmaf(e.x, w0, acc[rr]);
                acc[rr] = fmaf(e.y, w1, acc[rr]);
                acc[rr] = fmaf(e.z, w2, acc[rr]);
                acc[rr] = fmaf(e.w, w3, acc[rr]);
            }
        }
        #pragma unroll
        for (int rr = 0; rr < 8; rr++)
            sh1[(half*8+rr)*D1 + f] = fmaxf(acc[rr], 0.0f);
    }
    __syncthreads();

    // layer 2: each thread = one f (0..63), 4 rows
    {
        const int f = t & (D2-1);
        const int g = t >> 6;
        float acc[4];
        const float bias = b2[f];
        #pragma unroll
        for (int rr = 0; rr < 4; rr++) acc[rr] = bias;
        for (int d = 0; d < D1; d += 4) {
            const float w0 = W2[(d+0)*D2 + f];
            const float w1 = W2[(d+1)*D2 + f];
            const float w2_ = W2[(d+2)*D2 + f];
            const float w3 = W2[(d+3)*D2 + f];
            #pragma unroll
            for (int rr = 0; rr < 4; rr++) {
                const float4 h = *(const float4*)&sh1[(g*4+rr)*D1 + d];
                acc[rr] = fmaf(h.x, w0, acc[rr]);
                acc[rr] = fmaf(h.y, w1, acc[rr]);
                acc[rr] = fmaf(h.z, w2_, acc[rr]);
                acc[rr] = fmaf(h.w, w3, acc[rr]);
            }
        }
        #pragma unroll
        for (int rr = 0; rr < 4; rr++)
            sh2[(g*4+rr)*D2 + f] = fmaxf(acc[rr], 0.0f);
    }
    __syncthreads();

    // layer 3: 16 rows x 50 -> zT[b][f][n] (transposed for pair kernel coalescing)
    const int bb = (int)(row0 / NN);
    const int n0 = (int)(row0 - (long)bb*NN);
    for (int item = t; item < R1*NC; item += 256) {
        const int r = item / NC;
        const int f = item - r*NC;
        float acc = b3[f];
        for (int d = 0; d < D2; d++)
            acc = fmaf(sh2[r*D2 + d], W3[d*NC + f], acc);
        sz[r*NC + f] = acc;
        zT[((size_t)bb*NC + f)*NN + n0 + r] = acc;
    }
    __syncthreads();

    if (t < R1) {
        float s = 0.0f;
        #pragma unroll
        for (int k = 0; k < NC; k++) { const float v = sz[t*NC + k]; s = fmaf(v, v, s); }
        sq[row0 + t] = s;
    }
}

// ------- Kernel 2: fused pairwise dist -> exp(exp(-d/2)) -> softmax -> +eps renorm -------
// Block: 512 threads, TIB=8 i-rows, full j-row (4096). Thread t owns j = t*4+{0..3} and
// j = t*4+2048+{0..3}: every global load/store is a perfectly coalesced wave-contiguous float4.
// v2: __launch_bounds__(512,4) caps VGPR <=128 (4 waves/SIMD); explicit k+1 register
// prefetch of the zT j-vectors; sq loads hoisted above the k-loop.
__global__ __launch_bounds__(PTH, 4) void pair_kernel(
    const float* __restrict__ zT, const float* __restrict__ sq,
    float* __restrict__ out)
{
    const int t = threadIdx.x;
    const int b = blockIdx.x >> 9;               // / (NN/TIB) = 512
    const int i0 = (blockIdx.x & 511) * TIB;

    __shared__ __align__(16) float szi[NC][TIB]; // z_i fragments, k-major
    __shared__ float wsum[PTH/64][TIB];
    __shared__ float sS[TIB];

    const float* ztb = zT + (size_t)b * NC * NN;

    // stage z_i (8 rows x 50 k) into LDS — tiny gather from L2
    for (int idx = t; idx < NC*TIB; idx += PTH) {
        const int k = idx >> 3, ii = idx & 7;
        szi[k][ii] = ztb[(size_t)k*NN + i0 + ii];
    }

    // hoist sq loads (L1/L2 hits) — latency hides under staging + gemm
    const float* sqb = sq + (size_t)b * NN;
    const int j0 = t * 4;
    float sqi[TIB];
    #pragma unroll
    for (int ii = 0; ii < TIB; ii++) sqi[ii] = sqb[i0 + ii];   // broadcast, L1
    const float4 sja = *(const float4*)(sqb + j0);
    const float4 sjb = *(const float4*)(sqb + j0 + 2048);

    __syncthreads();

    float acc[TIB][JT];
    #pragma unroll
    for (int ii = 0; ii < TIB; ii++)
        #pragma unroll
        for (int jj = 0; jj < JT; jj++) acc[ii][jj] = 0.0f;

    // software-pipelined k-loop: register double-buffer on the coalesced zT loads
    float4 nj0 = *(const float4*)(ztb + j0);          // prefetch k=0
    float4 nj1 = *(const float4*)(ztb + j0 + 2048);
    #pragma unroll 1
    for (int k = 0; k < NC-1; k++) {
        const float4 zj0 = nj0, zj1 = nj1;
        nj0 = *(const float4*)(ztb + (size_t)(k+1)*NN + j0);          // prefetch k+1
        nj1 = *(const float4*)(ztb + (size_t)(k+1)*NN + j0 + 2048);
        const float4 zia = *(const float4*)&szi[k][0];                // LDS broadcast
        const float4 zib = *(const float4*)&szi[k][4];
        const float zi[8] = {zia.x, zia.y, zia.z, zia.w, zib.x, zib.y, zib.z, zib.w};
        const float zj[8] = {zj0.x, zj0.y, zj0.z, zj0.w, zj1.x, zj1.y, zj1.z, zj1.w};
        #pragma unroll
        for (int ii = 0; ii < TIB; ii++)
            #pragma unroll
            for (int jj = 0; jj < JT; jj++)
                acc[ii][jj] = fmaf(zi[ii], zj[jj], acc[ii][jj]);
    }
    {   // last iteration (k = NC-1), no prefetch
        const float4 zia = *(const float4*)&szi[NC-1][0];
        const float4 zib = *(const float4*)&szi[NC-1][4];
        const float zi[8] = {zia.x, zia.y, zia.z, zia.w, zib.x, zib.y, zib.z, zib.w};
        const float zj[8] = {nj0.x, nj0.y, nj0.z, nj0.w, nj1.x, nj1.y, nj1.z, nj1.w};
        #pragma unroll
        for (int ii = 0; ii < TIB; ii++)
            #pragma unroll
            for (int jj = 0; jj < JT; jj++)
                acc[ii][jj] = fmaf(zi[ii], zj[jj], acc[ii][jj]);
    }

    const float sqj[8] = {sja.x, sja.y, sja.z, sja.w, sjb.x, sjb.y, sjb.z, sjb.w};

    // dist -> e = exp(exp(-d/2)) in place, accumulate row sums
    float rsum[TIB];
    #pragma unroll
    for (int ii = 0; ii < TIB; ii++) {
        float s = 0.0f;
        #pragma unroll
        for (int jj = 0; jj < JT; jj++) {
            const float d = fmaxf(sqi[ii] + sqj[jj] - 2.0f*acc[ii][jj], 0.0f);
            const float e = __expf(__expf(-0.5f*d));
            acc[ii][jj] = e;
            s += e;
        }
        rsum[ii] = s;
    }

    // reduce rsum[8] across the block: wave shfl -> LDS -> final
    #pragma unroll
    for (int off = 32; off; off >>= 1)
        #pragma unroll
        for (int ii = 0; ii < TIB; ii++)
            rsum[ii] += __shfl_xor(rsum[ii], off, 64);
    const int wave = t >> 6, lane = t & 63;
    if (lane == 0) {
        #pragma unroll
        for (int ii = 0; ii < TIB; ii++) wsum[wave][ii] = rsum[ii];
    }
    __syncthreads();
    if (t < TIB) {
        float s = 0.0f;
        #pragma unroll
        for (int w = 0; w < PTH/64; w++) s += wsum[w][t];
        sS[t] = s;
    }
    __syncthreads();

    const float rn = 1.0f / (1.0f + (float)NN * 1e-6f);
    const float c = 1e-6f * rn;
    float* ob = out + ((size_t)(b*NN + i0)) * NN;
    #pragma unroll
    for (int ii = 0; ii < TIB; ii++) {
        const float is = rn / sS[ii];   // broadcast LDS read
        float4 v0, v1;
        v0.x = fmaf(acc[ii][0], is, c);
        v0.y = fmaf(acc[ii][1], is, c);
        v0.z = fmaf(acc[ii][2], is, c);
        v0.w = fmaf(acc[ii][3], is, c);
        v1.x = fmaf(acc[ii][4], is, c);
        v1.y = fmaf(acc[ii][5], is, c);
        v1.z = fmaf(acc[ii][6], is, c);
        v1.w = fmaf(acc[ii][7], is, c);
        *(float4*)(ob + (size_t)ii*NN + j0) = v0;          // coalesced 1KB/wave
        *(float4*)(ob + (size_t)ii*NN + j0 + 2048) = v1;   // coalesced 1KB/wave
    }
}

extern "C" void kernel_launch(void* const* d_in, const int* in_sizes, int n_in,
                              void* d_out, int out_size, void* d_ws, size_t ws_size,
                              hipStream_t stream) {
    const float* emb = (const float*)d_in[0];
    const float* W1  = (const float*)d_in[1];
    const float* b1  = (const float*)d_in[2];
    const float* W2  = (const float*)d_in[3];
    const float* b2  = (const float*)d_in[4];
    const float* W3  = (const float*)d_in[5];
    const float* b3  = (const float*)d_in[6];
    float* out = (float*)d_out;

    float* zT = (float*)d_ws;                       // NB*NC*NN floats (transposed)
    float* sq = zT + (size_t)NB*NC*NN;              // NB*NN floats

    mlp_kernel<<<NB*NN/R1, 256, 0, stream>>>(emb, W1, b1, W2, b2, W3, b3, zT, sq);
    pair_kernel<<<NB*(NN/TIB), PTH, 0, stream>>>(zT, sq, out);
}